// Round 1
// baseline (85.064 us; speedup 1.0000x reference)
//
#include <hip/hip_runtime.h>
#include <math.h>

// S4D kernel generation:
//   dt   = exp(log_dt)                          (H,)
//   A    = -exp(log_A_real) + i*A_imag          (H, N)
//   dtA  = A * dt
//   Ceff = C * (exp(dtA) - 1) / A               (H, N) complex
//   out[h,l] = 2 * Re( sum_n Ceff[h,n] * exp(dtA[h,n] * l) )   (H, L) f32
//
// Strategy: one block per h (256 threads). Lane t seeds w = Ceff * exp(dtA*t)
// with one __expf + __sincosf, then recurs w *= exp(dtA*256) to cover
// l = t + 256k, k = 0..CHUNK-1. Inner loop: 5 VALU ops/element, no
// transcendentals. Stores are lane-coalesced dwords.

#define H_DIM 1024
#define NHALF 32

template <int CHUNK>
__global__ __launch_bounds__(256) void s4d_kernel(
    const float* __restrict__ C_param,     // (H, NHALF, 2)
    const float* __restrict__ log_dt,      // (H,)
    const float* __restrict__ log_A_real,  // (H, NHALF)
    const float* __restrict__ A_imag,      // (H, NHALF)
    float* __restrict__ out,               // (H, L)
    int L)
{
    __shared__ float s_cr[NHALF], s_ci[NHALF];  // Ceff
    __shared__ float s_ar[NHALF], s_ai[NHALF];  // dtA
    __shared__ float s_sr[NHALF], s_si[NHALF];  // step = exp(dtA * 256)

    const int h   = blockIdx.x;
    const int tid = threadIdx.x;
    const int stride = 256;

    if (tid < NHALF) {
        const int n = tid;
        const float dt = __expf(log_dt[h]);
        const float Ar = -__expf(log_A_real[h * NHALF + n]);
        const float Ai = A_imag[h * NHALF + n];
        const float ar = Ar * dt;
        const float ai = Ai * dt;
        // E = exp(dtA)
        float es, ec;
        __sincosf(ai, &es, &ec);
        const float em = __expf(ar);
        const float Er = em * ec, Ei = em * es;
        // q = (E - 1) / A   (complex divide; |A| >= 0.5 always)
        const float nr = Er - 1.0f, ni = Ei;
        const float inv = 1.0f / (Ar * Ar + Ai * Ai);
        const float qr = (nr * Ar + ni * Ai) * inv;
        const float qi = (ni * Ar - nr * Ai) * inv;
        // Ceff = C * q
        const float Cr = C_param[(h * NHALF + n) * 2 + 0];
        const float Ci = C_param[(h * NHALF + n) * 2 + 1];
        s_cr[n] = Cr * qr - Ci * qi;
        s_ci[n] = Cr * qi + Ci * qr;
        s_ar[n] = ar;
        s_ai[n] = ai;
        // step = exp(dtA * stride)
        float ss, sc;
        __sincosf(ai * (float)stride, &ss, &sc);
        const float sm = __expf(ar * (float)stride);
        s_sr[n] = sm * sc;
        s_si[n] = sm * ss;
    }
    __syncthreads();

    float acc[CHUNK];
#pragma unroll
    for (int k = 0; k < CHUNK; ++k) acc[k] = 0.0f;

    const float t0 = (float)tid;
    for (int n = 0; n < NHALF; ++n) {
        const float cr = s_cr[n], ci = s_ci[n];
        const float ar = s_ar[n], ai = s_ai[n];
        const float sr = s_sr[n], si = s_si[n];
        // seed z = exp(dtA * t0)
        float zs, zc;
        __sincosf(ai * t0, &zs, &zc);
        const float zm = __expf(ar * t0);
        const float zr = zm * zc, zi = zm * zs;
        // fold Ceff in: w = Ceff * z
        float wr = cr * zr - ci * zi;
        float wi = cr * zi + ci * zr;
#pragma unroll
        for (int k = 0; k < CHUNK; ++k) {
            acc[k] += wr;                          // Re(Ceff * exp(dtA*l))
            const float nwr = fmaf(wr, sr, -wi * si);
            const float nwi = fmaf(wr, si,  wi * sr);
            wr = nwr;
            wi = nwi;
        }
    }

#pragma unroll
    for (int k = 0; k < CHUNK; ++k) {
        out[h * L + tid + k * stride] = 2.0f * acc[k];
    }
}

extern "C" void kernel_launch(void* const* d_in, const int* in_sizes, int n_in,
                              void* d_out, int out_size, void* d_ws, size_t ws_size,
                              hipStream_t stream) {
    const float* C_param    = (const float*)d_in[0];
    const float* log_dt     = (const float*)d_in[1];
    const float* log_A_real = (const float*)d_in[2];
    const float* A_imag     = (const float*)d_in[3];
    float* out = (float*)d_out;

    const int L = out_size / H_DIM;  // 4096 for this problem

    // CHUNK = L / 256 = 16
    s4d_kernel<16><<<dim3(H_DIM), dim3(256), 0, stream>>>(
        C_param, log_dt, log_A_real, A_imag, out, L);
}